// Round 9
// baseline (1038.224 us; speedup 1.0000x reference)
//
#include <hip/hip_runtime.h>

#define B_ 64
#define S_ 512
#define E_ 300
#define H_ 256
#define G_ 768  // 3*H

typedef _Float16 h2_t __attribute__((ext_vector_type(2)));
typedef unsigned u32x16 __attribute__((ext_vector_type(16)));

__device__ __forceinline__ unsigned pack_h2(float a, float b) {
  h2_t v;
  v.x = (_Float16)a;
  v.y = (_Float16)b;
  return __builtin_bit_cast(unsigned, v);
}

__device__ __forceinline__ float fdot2f(unsigned w, unsigned h, float acc) {
  return __builtin_amdgcn_fdot2(__builtin_bit_cast(h2_t, w),
                                __builtin_bit_cast(h2_t, h), acc, false);
}

// pack 32 consecutive floats into 16 half2 lanes of a u32x16 (pure SSA)
__device__ __forceinline__ u32x16 load_pack32(const float* __restrict__ src) {
  u32x16 d;
#pragma unroll
  for (int e = 0; e < 8; ++e) {
    float4 f = *(const float4*)(src + 4 * e);
    d[2 * e] = pack_h2(f.x, f.y);
    d[2 * e + 1] = pack_h2(f.z, f.w);
  }
  return d;
}

__device__ __forceinline__ float fast_sigmoid(float x) {
  return __builtin_amdgcn_rcpf(1.0f + __builtin_amdgcn_exp2f(-1.44269504f * x));
}
__device__ __forceinline__ float fast_tanh(float x) {
  float e = __builtin_amdgcn_exp2f(-2.88539008f * fabsf(x));
  return copysignf((1.0f - e) * __builtin_amdgcn_rcpf(1.0f + e), x);
}

// ---------------------------------------------------------------------------
// Kernel 1: embedding gather + mask.
// ---------------------------------------------------------------------------
__global__ void k_embed(const int* __restrict__ inds, const int* __restrict__ lens,
                        const float* __restrict__ table, float* __restrict__ out_emb,
                        float* __restrict__ out_mask) {
  const long total = (long)B_ * S_ * E_;
  for (long idx = (long)blockIdx.x * blockDim.x + threadIdx.x; idx < total;
       idx += (long)gridDim.x * blockDim.x) {
    int row = (int)(idx / E_);
    int e = (int)(idx - (long)row * E_);
    int b = row >> 9;
    int s = row & 511;
    bool valid = s < lens[b];
    float v = 0.0f;
    if (valid) v = table[(long)inds[row] * E_ + e];
    out_emb[idx] = v;
    if (e == 0) out_mask[row] = valid ? 1.0f : 0.0f;
  }
}

// ---------------------------------------------------------------------------
// Kernel 2: gx = emb @ w_ih^T + b_ih (+ b_hh folded in for r,z gates)
// [32768 x 300] x [300 x 768] -> f16
// ---------------------------------------------------------------------------
#define KC 30
__global__ __launch_bounds__(256) void k_gx(const float* __restrict__ A,
                                            const float* __restrict__ W,
                                            const float* __restrict__ b_ih,
                                            const float* __restrict__ b_hh,
                                            _Float16* __restrict__ gx) {
  __shared__ float As[KC][132];
  __shared__ float Ws[KC][132];
  const int tid = threadIdx.x;
  const int row0 = blockIdx.x * 128;
  const int col0 = blockIdx.y * 128;
  const int tx = tid & 15;
  const int ty = tid >> 4;

  float acc[8][8];
#pragma unroll
  for (int i = 0; i < 8; ++i)
#pragma unroll
    for (int j = 0; j < 8; ++j) acc[i][j] = 0.0f;

  for (int kt = 0; kt < E_ / KC; ++kt) {
    const int k0 = kt * KC;
#pragma unroll
    for (int u = 0; u < 15; ++u) {
      int idx = tid + u * 256;
      int r = idx / KC;
      int kk = idx - r * KC;
      As[kk][r] = A[(long)(row0 + r) * E_ + k0 + kk];
      Ws[kk][r] = W[(long)(col0 + r) * E_ + k0 + kk];
    }
    __syncthreads();
    for (int kk = 0; kk < KC; ++kk) {
      float4 a0 = *(const float4*)&As[kk][ty * 4];
      float4 a1 = *(const float4*)&As[kk][64 + ty * 4];
      float4 b0 = *(const float4*)&Ws[kk][tx * 4];
      float4 b1 = *(const float4*)&Ws[kk][64 + tx * 4];
      float av[8] = {a0.x, a0.y, a0.z, a0.w, a1.x, a1.y, a1.z, a1.w};
      float bv[8] = {b0.x, b0.y, b0.z, b0.w, b1.x, b1.y, b1.z, b1.w};
#pragma unroll
      for (int i = 0; i < 8; ++i)
#pragma unroll
        for (int j = 0; j < 8; ++j) acc[i][j] += av[i] * bv[j];
    }
    __syncthreads();
  }

#pragma unroll
  for (int i = 0; i < 8; ++i) {
    int r = row0 + ((i < 4) ? (ty * 4 + i) : (64 + ty * 4 + i - 4));
#pragma unroll
    for (int j = 0; j < 8; ++j) {
      int c = col0 + ((j < 4) ? (tx * 4 + j) : (64 + tx * 4 + j - 4));
      float bias = b_ih[c] + ((c < 2 * H_) ? b_hh[c] : 0.0f);  // fold r,z b_hh
      gx[(long)r * G_ + c] = (_Float16)(acc[i][j] + bias);
    }
  }
}

// ---------------------------------------------------------------------------
// Kernel 3: masked GRU scan. 64 blocks x 512 threads.
// KEY MECHANISM (round 9): the toolchain hard-caps arch VGPRs at 128 for
// this kernel (proven across lb/waves_per_eu/LDS-pad experiments r1-r8),
// so the 192 weight half2/thread can never all live in arch VGPRs.
// Fix: bank the z- and n-gate weights (128 u32) in AGPRs — 128 named
// scalar values defined via "=a" inline asm (v_accvgpr_write_b32) and
// consumed via "a"-operand asm (v_accvgpr_read_b32 + v_dot2_f32_f16).
// AGPRs are a separate 256-deep register class outside the 128-VGPR cap.
// The r-gate weights (64 u32, SSA u32x16) + ~45 misc stay in arch VGPRs.
// Everything else as r8: thread j (p=j>>1, hf=j&1) owns w_hh rows
// {p, H+p, 2H+p}, k in [128hf,+128); k-half partials combined via
// shfl_xor(1); h broadcast via double-buffered padded LDS (0 conflicts);
// one barrier/step; gx for t+1 prefetched during step t.
// ---------------------------------------------------------------------------
#define FOR16(M) M(0) M(1) M(2) M(3) M(4) M(5) M(6) M(7) \
                 M(8) M(9) M(10) M(11) M(12) M(13) M(14) M(15)

__global__ __launch_bounds__(512) __attribute__((amdgpu_waves_per_eu(2, 2))) void
k_gru(const float* __restrict__ w_hh, const float* __restrict__ b_hh,
      const int* __restrict__ lens, const _Float16* __restrict__ gx,
      float* __restrict__ feats, float* __restrict__ hid) {
  const int b = blockIdx.x;
  const int j = threadIdx.x;  // 0..511
  const int len = lens[b];

  __shared__ __align__(16) unsigned h2buf[2][2][68];  // [buf][k-half][64+4 pad]

  const int p = j >> 1;  // hidden unit 0..255
  const int hf = j & 1;  // k-half

  const float* s_r = w_hh + (long)p * H_ + 128 * hf;
  const float* s_z = w_hh + ((long)H_ + p) * H_ + 128 * hf;
  const float* s_n = w_hh + ((long)2 * H_ + p) * H_ + 128 * hf;

  // r-gate weights: 4 SSA u32x16 vectors in arch VGPRs (64 regs)
  u32x16 wr0 = load_pack32(s_r + 0), wr1 = load_pack32(s_r + 32),
         wr2 = load_pack32(s_r + 64), wr3 = load_pack32(s_r + 96);

  // z/n-gate weights: 128 named scalars homed in AGPRs.
#define DECL_ZN(c)                                      \
  unsigned wz##c##_0, wz##c##_1, wz##c##_2, wz##c##_3;  \
  unsigned wn##c##_0, wn##c##_1, wn##c##_2, wn##c##_3;
  FOR16(DECL_ZN)
#undef DECL_ZN

#define AWRITE(dst, val) \
  asm("v_accvgpr_write_b32 %0, %1" : "=a"(dst) : "v"(val))

#define LOAD_ZN(c)                                  \
  {                                                 \
    float4 f0 = *(const float4*)(s_z + 8 * (c));    \
    float4 f1 = *(const float4*)(s_z + 8 * (c) + 4);\
    AWRITE(wz##c##_0, pack_h2(f0.x, f0.y));         \
    AWRITE(wz##c##_1, pack_h2(f0.z, f0.w));         \
    AWRITE(wz##c##_2, pack_h2(f1.x, f1.y));         \
    AWRITE(wz##c##_3, pack_h2(f1.z, f1.w));         \
    float4 g0 = *(const float4*)(s_n + 8 * (c));    \
    float4 g1 = *(const float4*)(s_n + 8 * (c) + 4);\
    AWRITE(wn##c##_0, pack_h2(g0.x, g0.y));         \
    AWRITE(wn##c##_1, pack_h2(g0.z, g0.w));         \
    AWRITE(wn##c##_2, pack_h2(g1.x, g1.y));         \
    AWRITE(wn##c##_3, pack_h2(g1.z, g1.w));         \
  }
  FOR16(LOAD_ZN)
#undef LOAD_ZN

  const float bias_n = b_hh[2 * H_ + p];  // r,z biases folded into gx
  float hreg = 0.0f;

  if (j < 272) ((unsigned*)h2buf)[j] = 0u;  // h0 = 0 (both buffers + pads)
  __syncthreads();

  const _Float16* gxb = gx + (long)b * S_ * G_;
  float gxr = (float)gxb[p];
  float gxz = (float)gxb[H_ + p];
  float gxn = (float)gxb[2 * H_ + p];

  // AGPR dot: read weight from AGPR, dot into acc. Single asm unit so the
  // accvgpr_read cannot be hoisted away from its (loop-variant) dot.
#define ADOT(acc, w, h)                              \
  {                                                  \
    unsigned t_;                                     \
    asm("v_accvgpr_read_b32 %1, %2\n\t"              \
        "v_dot2_f32_f16 %0, %1, %3, %0"              \
        : "+v"(acc), "=&v"(t_)                       \
        : "a"(w), "v"(h));                           \
  }

  int cur = 0;
  for (int t = 0; t < len; ++t) {
    const int tn = (t + 1 < len) ? (t + 1) : t;
    const _Float16* gxt = gxb + (long)tn * G_;
    _Float16 nr = gxt[p];
    _Float16 nz = gxt[H_ + p];
    _Float16 nn = gxt[2 * H_ + p];

    float a0 = 0.f, a1 = 0.f, a2 = 0.f;

// WRV = r-gate vector for this chunk, E = literal c&3, c = literal 0..15
#define DOTC(WRV, E, c)                                      \
  {                                                          \
    float4 hv = *(const float4*)&h2buf[cur][hf][4 * (c)];    \
    unsigned hq0 = __builtin_bit_cast(unsigned, hv.x);       \
    unsigned hq1 = __builtin_bit_cast(unsigned, hv.y);       \
    unsigned hq2 = __builtin_bit_cast(unsigned, hv.z);       \
    unsigned hq3 = __builtin_bit_cast(unsigned, hv.w);       \
    a0 = fdot2f(WRV[4 * (E) + 0], hq0, a0);                  \
    a0 = fdot2f(WRV[4 * (E) + 1], hq1, a0);                  \
    a0 = fdot2f(WRV[4 * (E) + 2], hq2, a0);                  \
    a0 = fdot2f(WRV[4 * (E) + 3], hq3, a0);                  \
    ADOT(a1, wz##c##_0, hq0);                                \
    ADOT(a1, wz##c##_1, hq1);                                \
    ADOT(a1, wz##c##_2, hq2);                                \
    ADOT(a1, wz##c##_3, hq3);                                \
    ADOT(a2, wn##c##_0, hq0);                                \
    ADOT(a2, wn##c##_1, hq1);                                \
    ADOT(a2, wn##c##_2, hq2);                                \
    ADOT(a2, wn##c##_3, hq3);                                \
  }

    DOTC(wr0, 0, 0)
    DOTC(wr0, 1, 1)
    DOTC(wr0, 2, 2)
    DOTC(wr0, 3, 3)
    DOTC(wr1, 0, 4)
    DOTC(wr1, 1, 5)
    DOTC(wr1, 2, 6)
    DOTC(wr1, 3, 7)
    DOTC(wr2, 0, 8)
    DOTC(wr2, 1, 9)
    DOTC(wr2, 2, 10)
    DOTC(wr2, 3, 11)
    DOTC(wr3, 0, 12)
    DOTC(wr3, 1, 13)
    DOTC(wr3, 2, 14)
    DOTC(wr3, 3, 15)
#undef DOTC

    // combine the two k-halves (lanes j, j^1); both lanes get full sums
    a0 += __shfl_xor(a0, 1);
    a1 += __shfl_xor(a1, 1);
    a2 += __shfl_xor(a2, 1);

    // gates for unit p (duplicated across the pair — free)
    float r = fast_sigmoid(gxr + a0);
    float z = fast_sigmoid(gxz + a1);
    float n = fast_tanh(gxn + r * (a2 + bias_n));
    hreg = (1.0f - z) * n + z * hreg;

    if (hf == 0) feats[((long)b * S_ + t) * H_ + p] = hreg;

    // pack h into the other buffer: lane 4i holds h[2i], lane 4i+2 h[2i+1]
    float hother = __shfl_xor(hreg, 2);
    if ((j & 3) == 0) {
      int i = j >> 2;  // half2 index 0..127
      h2buf[cur ^ 1][i >> 6][i & 63] = pack_h2(hreg, hother);
    }

    __syncthreads();
    cur ^= 1;
    gxr = (float)nr;
    gxz = (float)nz;
    gxn = (float)nn;
  }

  // zero feats past len (reference masks them to 0)
  {
    const long tail = (long)(S_ - len) * H_;
    float* dst = feats + ((long)b * S_ + len) * H_;
    for (long idx = j; idx < tail; idx += 512) dst[idx] = 0.0f;
  }
  if (hf == 0) hid[b * H_ + p] = hreg;
}

// ---------------------------------------------------------------------------
extern "C" void kernel_launch(void* const* d_in, const int* in_sizes, int n_in,
                              void* d_out, int out_size, void* d_ws, size_t ws_size,
                              hipStream_t stream) {
  const int* inds = (const int*)d_in[0];
  const int* lens = (const int*)d_in[1];
  const float* table = (const float*)d_in[2];
  const float* w_ih = (const float*)d_in[3];
  const float* w_hh = (const float*)d_in[4];
  const float* b_ih = (const float*)d_in[5];
  const float* b_hh = (const float*)d_in[6];

  float* out = (float*)d_out;
  float* out_emb = out;                              // B*S*E
  float* out_feats = out + (long)B_ * S_ * E_;       // B*S*H
  float* out_mask = out_feats + (long)B_ * S_ * H_;  // B*S
  float* out_hid = out_mask + (long)B_ * S_;         // B*H

  _Float16* gx = (_Float16*)d_ws;  // B*S*3H f16

  k_embed<<<2048, 256, 0, stream>>>(inds, lens, table, out_emb, out_mask);
  dim3 g2(32768 / 128, G_ / 128);
  k_gx<<<g2, 256, 0, stream>>>(out_emb, w_ih, b_ih, b_hh, gx);
  k_gru<<<B_, 512, 0, stream>>>(w_hh, b_hh, lens, gx, out_feats, out_hid);
}

// Round 10
// 782.268 us; speedup vs baseline: 1.3272x; 1.3272x over previous
//
#include <hip/hip_runtime.h>

#define B_ 64
#define S_ 512
#define E_ 300
#define H_ 256
#define G_ 768  // 3*H

typedef _Float16 h2_t __attribute__((ext_vector_type(2)));

__device__ __forceinline__ unsigned pack_h2(float a, float b) {
  h2_t v;
  v.x = (_Float16)a;
  v.y = (_Float16)b;
  return __builtin_bit_cast(unsigned, v);
}

__device__ __forceinline__ float fdot2f(unsigned w, unsigned h, float acc) {
  return __builtin_amdgcn_fdot2(__builtin_bit_cast(h2_t, w),
                                __builtin_bit_cast(h2_t, h), acc, false);
}

__device__ __forceinline__ float fast_sigmoid(float x) {
  return __builtin_amdgcn_rcpf(1.0f + __builtin_amdgcn_exp2f(-1.44269504f * x));
}
__device__ __forceinline__ float fast_tanh(float x) {
  float e = __builtin_amdgcn_exp2f(-2.88539008f * fabsf(x));
  return copysignf((1.0f - e) * __builtin_amdgcn_rcpf(1.0f + e), x);
}

// ---------------------------------------------------------------------------
// Kernel 1: embedding gather + mask.
// ---------------------------------------------------------------------------
__global__ void k_embed(const int* __restrict__ inds, const int* __restrict__ lens,
                        const float* __restrict__ table, float* __restrict__ out_emb,
                        float* __restrict__ out_mask) {
  const long total = (long)B_ * S_ * E_;
  for (long idx = (long)blockIdx.x * blockDim.x + threadIdx.x; idx < total;
       idx += (long)gridDim.x * blockDim.x) {
    int row = (int)(idx / E_);
    int e = (int)(idx - (long)row * E_);
    int b = row >> 9;
    int s = row & 511;
    bool valid = s < lens[b];
    float v = 0.0f;
    if (valid) v = table[(long)inds[row] * E_ + e];
    out_emb[idx] = v;
    if (e == 0) out_mask[row] = valid ? 1.0f : 0.0f;
  }
}

// ---------------------------------------------------------------------------
// Kernel 2: gx = emb @ w_ih^T + b_ih (+ b_hh folded in for r,z gates)
// [32768 x 300] x [300 x 768] -> f16
// ---------------------------------------------------------------------------
#define KC 30
__global__ __launch_bounds__(256) void k_gx(const float* __restrict__ A,
                                            const float* __restrict__ W,
                                            const float* __restrict__ b_ih,
                                            const float* __restrict__ b_hh,
                                            _Float16* __restrict__ gx) {
  __shared__ float As[KC][132];
  __shared__ float Ws[KC][132];
  const int tid = threadIdx.x;
  const int row0 = blockIdx.x * 128;
  const int col0 = blockIdx.y * 128;
  const int tx = tid & 15;
  const int ty = tid >> 4;

  float acc[8][8];
#pragma unroll
  for (int i = 0; i < 8; ++i)
#pragma unroll
    for (int j = 0; j < 8; ++j) acc[i][j] = 0.0f;

  for (int kt = 0; kt < E_ / KC; ++kt) {
    const int k0 = kt * KC;
#pragma unroll
    for (int u = 0; u < 15; ++u) {
      int idx = tid + u * 256;
      int r = idx / KC;
      int kk = idx - r * KC;
      As[kk][r] = A[(long)(row0 + r) * E_ + k0 + kk];
      Ws[kk][r] = W[(long)(col0 + r) * E_ + k0 + kk];
    }
    __syncthreads();
    for (int kk = 0; kk < KC; ++kk) {
      float4 a0 = *(const float4*)&As[kk][ty * 4];
      float4 a1 = *(const float4*)&As[kk][64 + ty * 4];
      float4 b0 = *(const float4*)&Ws[kk][tx * 4];
      float4 b1 = *(const float4*)&Ws[kk][64 + tx * 4];
      float av[8] = {a0.x, a0.y, a0.z, a0.w, a1.x, a1.y, a1.z, a1.w};
      float bv[8] = {b0.x, b0.y, b0.z, b0.w, b1.x, b1.y, b1.z, b1.w};
#pragma unroll
      for (int i = 0; i < 8; ++i)
#pragma unroll
        for (int j = 0; j < 8; ++j) acc[i][j] += av[i] * bv[j];
    }
    __syncthreads();
  }

#pragma unroll
  for (int i = 0; i < 8; ++i) {
    int r = row0 + ((i < 4) ? (ty * 4 + i) : (64 + ty * 4 + i - 4));
#pragma unroll
    for (int j = 0; j < 8; ++j) {
      int c = col0 + ((j < 4) ? (tx * 4 + j) : (64 + tx * 4 + j - 4));
      float bias = b_ih[c] + ((c < 2 * H_) ? b_hh[c] : 0.0f);  // fold r,z b_hh
      gx[(long)r * G_ + c] = (_Float16)(acc[i][j] + bias);
    }
  }
}

// ---------------------------------------------------------------------------
// Kernel 3: masked GRU scan. 64 blocks x 512 threads.
// KEY MECHANISM (round 10): rounds 1-8 spilled the weights because they were
// held in 16-wide ext_vector tuples — greedy RA must place each u32x16 as a
// CONTIGUOUS aligned 16-reg tuple; twelve such tuples fragment the file and
// the allocator spills whole tuples (the "128 cap" was tuple-allocation
// failure, not an occupancy target: r8 proved occupancy pinning alone does
// not help, r9 proved the values fit fine when banked elsewhere).
// Fix: 192 INDIVIDUALLY-NAMED scalar unsigned variables (token-pasted
// names, no arrays, no tuples, no asm). 192 independent single-reg live
// ranges place anywhere in the 512-reg unified file.
// Thread j (p=j>>1, hf=j&1): w_hh rows {p, H+p, 2H+p}, k in [128hf,+128).
// k-half partials combined with shfl_xor(1); both lanes compute the gates.
// h broadcast via double-buffered padded LDS (0 conflicts measured).
// One barrier per step; gx for t+1 prefetched during step t.
// ---------------------------------------------------------------------------
#define FOR16(M) M(0) M(1) M(2) M(3) M(4) M(5) M(6) M(7) \
                 M(8) M(9) M(10) M(11) M(12) M(13) M(14) M(15)

__global__ __launch_bounds__(512) __attribute__((amdgpu_waves_per_eu(2, 2))) void
k_gru(const float* __restrict__ w_hh, const float* __restrict__ b_hh,
      const int* __restrict__ lens, const _Float16* __restrict__ gx,
      float* __restrict__ feats, float* __restrict__ hid) {
  const int b = blockIdx.x;
  const int j = threadIdx.x;  // 0..511
  const int len = lens[b];

  __shared__ __align__(16) unsigned h2buf[2][2][68];  // [buf][k-half][64+4 pad]

  const int p = j >> 1;  // hidden unit 0..255
  const int hf = j & 1;  // k-half

  const float* s_r = w_hh + (long)p * H_ + 128 * hf;
  const float* s_z = w_hh + ((long)H_ + p) * H_ + 128 * hf;
  const float* s_n = w_hh + ((long)2 * H_ + p) * H_ + 128 * hf;

  // 192 named scalar weight registers: gate x chunk(0..15) x quad(0..3).
#define DECL_W(c)                                              \
  unsigned wr##c##_0, wr##c##_1, wr##c##_2, wr##c##_3;         \
  unsigned wz##c##_0, wz##c##_1, wz##c##_2, wz##c##_3;         \
  unsigned wn##c##_0, wn##c##_1, wn##c##_2, wn##c##_3;
  FOR16(DECL_W)
#undef DECL_W

#define LOAD_W(c)                                              \
  {                                                            \
    float4 f0 = *(const float4*)(s_r + 8 * (c));               \
    float4 f1 = *(const float4*)(s_r + 8 * (c) + 4);           \
    wr##c##_0 = pack_h2(f0.x, f0.y);                           \
    wr##c##_1 = pack_h2(f0.z, f0.w);                           \
    wr##c##_2 = pack_h2(f1.x, f1.y);                           \
    wr##c##_3 = pack_h2(f1.z, f1.w);                           \
    float4 g0 = *(const float4*)(s_z + 8 * (c));               \
    float4 g1 = *(const float4*)(s_z + 8 * (c) + 4);           \
    wz##c##_0 = pack_h2(g0.x, g0.y);                           \
    wz##c##_1 = pack_h2(g0.z, g0.w);                           \
    wz##c##_2 = pack_h2(g1.x, g1.y);                           \
    wz##c##_3 = pack_h2(g1.z, g1.w);                           \
    float4 e0 = *(const float4*)(s_n + 8 * (c));               \
    float4 e1 = *(const float4*)(s_n + 8 * (c) + 4);           \
    wn##c##_0 = pack_h2(e0.x, e0.y);                           \
    wn##c##_1 = pack_h2(e0.z, e0.w);                           \
    wn##c##_2 = pack_h2(e1.x, e1.y);                           \
    wn##c##_3 = pack_h2(e1.z, e1.w);                           \
  }
  FOR16(LOAD_W)
#undef LOAD_W

  const float bias_n = b_hh[2 * H_ + p];  // r,z biases folded into gx
  float hreg = 0.0f;

  if (j < 272) ((unsigned*)h2buf)[j] = 0u;  // h0 = 0 (both buffers + pads)
  __syncthreads();

  const _Float16* gxb = gx + (long)b * S_ * G_;
  float gxr = (float)gxb[p];
  float gxz = (float)gxb[H_ + p];
  float gxn = (float)gxb[2 * H_ + p];

  int cur = 0;
  for (int t = 0; t < len; ++t) {
    const int tn = (t + 1 < len) ? (t + 1) : t;
    const _Float16* gxt = gxb + (long)tn * G_;
    _Float16 nr = gxt[p];
    _Float16 nz = gxt[H_ + p];
    _Float16 nn = gxt[2 * H_ + p];

    float a0 = 0.f, a1 = 0.f, a2 = 0.f;

#define DOTC(c)                                               \
  {                                                           \
    float4 hv = *(const float4*)&h2buf[cur][hf][4 * (c)];     \
    unsigned hq0 = __builtin_bit_cast(unsigned, hv.x);        \
    unsigned hq1 = __builtin_bit_cast(unsigned, hv.y);        \
    unsigned hq2 = __builtin_bit_cast(unsigned, hv.z);        \
    unsigned hq3 = __builtin_bit_cast(unsigned, hv.w);        \
    a0 = fdot2f(wr##c##_0, hq0, a0);                          \
    a0 = fdot2f(wr##c##_1, hq1, a0);                          \
    a0 = fdot2f(wr##c##_2, hq2, a0);                          \
    a0 = fdot2f(wr##c##_3, hq3, a0);                          \
    a1 = fdot2f(wz##c##_0, hq0, a1);                          \
    a1 = fdot2f(wz##c##_1, hq1, a1);                          \
    a1 = fdot2f(wz##c##_2, hq2, a1);                          \
    a1 = fdot2f(wz##c##_3, hq3, a1);                          \
    a2 = fdot2f(wn##c##_0, hq0, a2);                          \
    a2 = fdot2f(wn##c##_1, hq1, a2);                          \
    a2 = fdot2f(wn##c##_2, hq2, a2);                          \
    a2 = fdot2f(wn##c##_3, hq3, a2);                          \
  }
    FOR16(DOTC)
#undef DOTC

    // combine the two k-halves (lanes j, j^1); both lanes get full sums
    a0 += __shfl_xor(a0, 1);
    a1 += __shfl_xor(a1, 1);
    a2 += __shfl_xor(a2, 1);

    // gates for unit p (duplicated across the pair — free)
    float r = fast_sigmoid(gxr + a0);
    float z = fast_sigmoid(gxz + a1);
    float n = fast_tanh(gxn + r * (a2 + bias_n));
    hreg = (1.0f - z) * n + z * hreg;

    if (hf == 0) feats[((long)b * S_ + t) * H_ + p] = hreg;

    // pack h into the other buffer: lane 4i holds h[2i], lane 4i+2 h[2i+1]
    float hother = __shfl_xor(hreg, 2);
    if ((j & 3) == 0) {
      int i = j >> 2;  // half2 index 0..127
      h2buf[cur ^ 1][i >> 6][i & 63] = pack_h2(hreg, hother);
    }

    __syncthreads();
    cur ^= 1;
    gxr = (float)nr;
    gxz = (float)nz;
    gxn = (float)nn;
  }

  // zero feats past len (reference masks them to 0)
  {
    const long tail = (long)(S_ - len) * H_;
    float* dst = feats + ((long)b * S_ + len) * H_;
    for (long idx = j; idx < tail; idx += 512) dst[idx] = 0.0f;
  }
  if (hf == 0) hid[b * H_ + p] = hreg;
}

// ---------------------------------------------------------------------------
extern "C" void kernel_launch(void* const* d_in, const int* in_sizes, int n_in,
                              void* d_out, int out_size, void* d_ws, size_t ws_size,
                              hipStream_t stream) {
  const int* inds = (const int*)d_in[0];
  const int* lens = (const int*)d_in[1];
  const float* table = (const float*)d_in[2];
  const float* w_ih = (const float*)d_in[3];
  const float* w_hh = (const float*)d_in[4];
  const float* b_ih = (const float*)d_in[5];
  const float* b_hh = (const float*)d_in[6];

  float* out = (float*)d_out;
  float* out_emb = out;                              // B*S*E
  float* out_feats = out + (long)B_ * S_ * E_;       // B*S*H
  float* out_mask = out_feats + (long)B_ * S_ * H_;  // B*S
  float* out_hid = out_mask + (long)B_ * S_;         // B*H

  _Float16* gx = (_Float16*)d_ws;  // B*S*3H f16

  k_embed<<<2048, 256, 0, stream>>>(inds, lens, table, out_emb, out_mask);
  dim3 g2(32768 / 128, G_ / 128);
  k_gx<<<g2, 256, 0, stream>>>(out_emb, w_ih, b_ih, b_hh, gx);
  k_gru<<<B_, 512, 0, stream>>>(w_hh, b_hh, lens, gx, out_feats, out_hid);
}